// Round 8
// baseline (1890.450 us; speedup 1.0000x reference)
//
#include <hip/hip_runtime.h>
#include <math.h>

#define H 43
#define H3 129
#define HP 64                     // padded fp16 row -> 128B
#define WSTR 132                  // padded weight row stride (3 gates x 44)
#define NN 100000
#define NE 1600000
#define NG 2048
#define FFD 392
#define NLB 138
#define SB 256
#define NBLK ((NN + SB - 1) / SB) // 391
#define NXCD 8
#define SHARD 12544               // 98 * 128 node-shard per XCD
#define GT_BLOCKS (NXCD * 196)    // conv grid: 64-node tiles
#define GR_BLOCKS (NXCD * 98)     // gru grid: 128-node blocks
#define GA_BLOCKS (NXCD * (SHARD / 4)) // gather grid, 4 nodes/block
#define FBLK 2048
#define CHUNK ((NE + 255) / 256)  // 6250

// ---------- CSR build (XCD-sharded by dst range) ----------
__global__ void hist_sh(const int* __restrict__ dst, int* __restrict__ deg) {
    int g = blockIdx.x & (NXCD - 1);
    int i = blockIdx.x >> 3;
    int lo = g * SHARD, hi = min(lo + SHARD, NN);
    int e0 = i * CHUNK, e1 = min(NE, e0 + CHUNK);
    for (int e = e0 + threadIdx.x; e < e1; e += blockDim.x) {
        int d = dst[e];
        if (d >= lo && d < hi) atomicAdd(&deg[d], 1);
    }
}

__global__ void fill_sh(const int* __restrict__ src, const int* __restrict__ dst,
                        int* __restrict__ pos, int* __restrict__ eadj) {
    int g = blockIdx.x & (NXCD - 1);
    int i = blockIdx.x >> 3;
    int lo = g * SHARD, hi = min(lo + SHARD, NN);
    int e0 = i * CHUNK, e1 = min(NE, e0 + CHUNK);
    for (int e = e0 + threadIdx.x; e < e1; e += blockDim.x) {
        int d = dst[e];
        if (d >= lo && d < hi) {
            int slot = atomicAdd(&pos[d], 1);
            eadj[slot] = src[e];
        }
    }
}

__global__ void scan1(const int* __restrict__ deg, int* __restrict__ tmp, int* __restrict__ bsum) {
    __shared__ int s[SB];
    int i = blockIdx.x * SB + threadIdx.x;
    int v = (i < NN) ? deg[i] : 0;
    s[threadIdx.x] = v;
    __syncthreads();
    for (int off = 1; off < SB; off <<= 1) {
        int t = (threadIdx.x >= (unsigned)off) ? s[threadIdx.x - off] : 0;
        __syncthreads();
        s[threadIdx.x] += t;
        __syncthreads();
    }
    if (i < NN) tmp[i] = s[threadIdx.x];
    if (threadIdx.x == SB - 1) bsum[blockIdx.x] = s[SB - 1];
}

__global__ void scan2(const int* __restrict__ bsum, int* __restrict__ boff) {
    __shared__ int s[512];
    int v = (threadIdx.x < NBLK) ? bsum[threadIdx.x] : 0;
    s[threadIdx.x] = v;
    __syncthreads();
    for (int off = 1; off < 512; off <<= 1) {
        int t = (threadIdx.x >= (unsigned)off) ? s[threadIdx.x - off] : 0;
        __syncthreads();
        s[threadIdx.x] += t;
        __syncthreads();
    }
    boff[threadIdx.x] = s[threadIdx.x] - v; // exclusive
}

__global__ void scan3(const int* __restrict__ deg, const int* __restrict__ tmp,
                      const int* __restrict__ boff, int* __restrict__ rowptr) {
    int i = blockIdx.x * blockDim.x + threadIdx.x;
    if (i < NN) rowptr[i] = tmp[i] - deg[i] + boff[i / SB];
    if (i == NN) rowptr[NN] = NE;
}

__global__ void copy_pos(const int* __restrict__ rowptr, int* __restrict__ pos) {
    int i = blockIdx.x * blockDim.x + threadIdx.x;
    if (i < NN) pos[i] = rowptr[i];
}

// ---------- Wc_p[l][k][gate*44+f] = (W[l] @ W_ih^T)[k][gate*43+f], padded ----------
__global__ void wc_build(const float* __restrict__ W, const float* __restrict__ W_ih,
                         float* __restrict__ Wc_p) {
    int t = blockIdx.x * blockDim.x + threadIdx.x;
    if (t >= 5 * H * H3) return;
    int l = t / (H * H3);
    int rem = t % (H * H3);
    int k = rem / H3, j = rem % H3;
    int gate = j / H, f = j % H;
    const float* Wl = W + l * H * H;
    float acc = 0.f;
#pragma unroll
    for (int c = 0; c < H; ++c) acc += Wl[k * H + c] * W_ih[j * H + c];
    Wc_p[(size_t)l * H * WSTR + k * WSTR + gate * 44 + f] = acc;
}

// ---------- Wh_p[k][gate*44+f] = W_hh[gate*43+f][k] (transposed, padded) ----------
__global__ void wh_pad(const float* __restrict__ W_hh, float* __restrict__ Wh_p) {
    int t = blockIdx.x * blockDim.x + threadIdx.x;
    if (t >= H * H3) return;
    int k = t / H3, j = t % H3;
    int gate = j / H, f = j % H;
    Wh_p[k * WSTR + gate * 44 + f] = W_hh[j * H + k];
}

// ---------- generic transpose: At[j*R + i] = A[i*C + j] ----------
__global__ void tr_mat(const float* __restrict__ A, float* __restrict__ At, int R, int C) {
    int t = blockIdx.x * blockDim.x + threadIdx.x;
    if (t >= R * C) return;
    int i = t / C, j = t % C;
    At[(size_t)j * R + i] = A[t];
}

// ---------- seed: hTb = x^T (feature-major), hh = fp16 padded rows ----------
__global__ void conv_xT(const float* __restrict__ x, float* __restrict__ hT,
                        _Float16* __restrict__ hh) {
    int g = blockIdx.x & (NXCD - 1);
    int t = blockIdx.x >> 3;
    int n0 = g * SHARD + t * 64;
    for (int i = threadIdx.x; i < 64 * H; i += 256) {
        int nl = i / H, f = i % H;
        int n = n0 + nl;
        if (n < NN) hT[f * NN + n] = x[n * H + f];
    }
    for (int i = threadIdx.x; i < 64 * HP; i += 256) {
        int nl = i >> 6, f = i & (HP - 1);
        int n = n0 + nl;
        if (n < NN) hh[(size_t)n * HP + f] = (f < H) ? (_Float16)x[n * H + f] : (_Float16)0.f;
    }
}

// ---------- gather: aggT[f][n] = sum over incoming edges of hh[src][f] ----------
__global__ __launch_bounds__(256) void gather_t(const _Float16* __restrict__ hh,
                                                const int* __restrict__ rowptr,
                                                const int* __restrict__ eadj,
                                                float* __restrict__ aggT) {
    int g = blockIdx.x & (NXCD - 1);
    int i = blockIdx.x >> 3;
    int wid = g * SHARD + i * 4 + (threadIdx.x >> 6);
    int lane = threadIdx.x & 63;
    if (wid >= NN) return;
    int beg = rowptr[wid], end = rowptr[wid + 1];
    int fc = (lane < H) ? lane : 0;
    float acc = 0.f;
    for (int base = beg; base < end; base += 64) {
        int cnt = min(64, end - base);
        int idx = (base + lane < end) ? eadj[base + lane] : 0;
        int r = 0;
        for (; r + 8 <= cnt; r += 8) {
            int s0 = __shfl(idx, r + 0), s1 = __shfl(idx, r + 1);
            int s2 = __shfl(idx, r + 2), s3 = __shfl(idx, r + 3);
            int s4 = __shfl(idx, r + 4), s5 = __shfl(idx, r + 5);
            int s6 = __shfl(idx, r + 6), s7 = __shfl(idx, r + 7);
            float v0 = (float)hh[(size_t)s0 * HP + fc];
            float v1 = (float)hh[(size_t)s1 * HP + fc];
            float v2 = (float)hh[(size_t)s2 * HP + fc];
            float v3 = (float)hh[(size_t)s3 * HP + fc];
            float v4 = (float)hh[(size_t)s4 * HP + fc];
            float v5 = (float)hh[(size_t)s5 * HP + fc];
            float v6 = (float)hh[(size_t)s6 * HP + fc];
            float v7 = (float)hh[(size_t)s7 * HP + fc];
            acc += ((v0 + v1) + (v2 + v3)) + ((v4 + v5) + (v6 + v7));
        }
        if (r + 4 <= cnt) {
            int s0 = __shfl(idx, r + 0), s1 = __shfl(idx, r + 1);
            int s2 = __shfl(idx, r + 2), s3 = __shfl(idx, r + 3);
            float v0 = (float)hh[(size_t)s0 * HP + fc];
            float v1 = (float)hh[(size_t)s1 * HP + fc];
            float v2 = (float)hh[(size_t)s2 * HP + fc];
            float v3 = (float)hh[(size_t)s3 * HP + fc];
            acc += (v0 + v1) + (v2 + v3);
            r += 4;
        }
        for (; r < cnt; ++r) {
            int s = __shfl(idx, r);
            acc += (float)hh[(size_t)s * HP + fc];
        }
    }
    if (lane < H) aggT[lane * NN + wid] = acc;
}

// ---------- GRU v2: inputs-in-registers, f-outer, scalar-pipe weights ----------
// Block = 128 nodes, 4 waves = 2 node-subgroups x 2 feature-halves.
// Each lane: load a[43], hv[43] once (coalesced, reused 129x). Loop 4-feature
// blocks: 16 accumulators; 24 weights/k from padded rows via wave-uniform
// 16B-aligned addresses -> s_load_dwordx4 on the scalar pipe (no VGPR cost).
__global__ __launch_bounds__(256, 4) void gru_t(const float* __restrict__ aggT,
                                                const float* __restrict__ hinT,
                                                const float* __restrict__ Wc_l,
                                                const float* __restrict__ Wh_p,
                                                const float* __restrict__ b_ih,
                                                const float* __restrict__ b_hh,
                                                float* __restrict__ houtT,
                                                _Float16* __restrict__ hh) {
    int g = blockIdx.x & (NXCD - 1);
    int t = blockIdx.x >> 3;
    int lane = threadIdx.x & 63;
    int w = __builtin_amdgcn_readfirstlane(threadIdx.x >> 6);
    int ng = w >> 1;      // node subgroup 0/1
    int fh = w & 1;       // feature half 0/1
    int n = g * SHARD + t * 128 + ng * 64 + lane;
    bool act = (n < NN);
    int nc = act ? n : (NN - 1);

    float a[H], hv[H];
#pragma unroll
    for (int k = 0; k < H; ++k) {
        a[k]  = aggT[k * NN + nc];
        hv[k] = hinT[k * NN + nc];
    }

    int fb0 = fh ? 24 : 0;
    int fbN = fh ? 5 : 6;  // fh0: f 0..23, fh1: f 24..43 (43 masked)

    for (int fi = 0; fi < fbN; ++fi) {
        int f0 = fb0 + fi * 4;
        const float* wc = Wc_l + f0;
        const float* wh = Wh_p + f0;
        float sr[4] = {0.f, 0.f, 0.f, 0.f};
        float sz[4] = {0.f, 0.f, 0.f, 0.f};
        float sn[4] = {0.f, 0.f, 0.f, 0.f};
        float sh[4] = {0.f, 0.f, 0.f, 0.f};
#pragma unroll
        for (int k = 0; k < H; ++k) {
            float ak = a[k], hk = hv[k];
            const float* wck = wc + k * WSTR;
            const float* whk = wh + k * WSTR;
#pragma unroll
            for (int j = 0; j < 4; ++j) {
                sr[j] += ak * wck[j]      + hk * whk[j];
                sz[j] += ak * wck[44 + j] + hk * whk[44 + j];
                sn[j] += ak * wck[88 + j];
                sh[j] += hk * whk[88 + j];
            }
        }
#pragma unroll
        for (int j = 0; j < 4; ++j) {
            int f = f0 + j;
            if (f < H) {
                float gr = sr[j] + b_ih[f] + b_hh[f];
                float gz = sz[j] + b_ih[H + f] + b_hh[H + f];
                float r = 1.f / (1.f + __expf(-gr));
                float z = 1.f / (1.f + __expf(-gz));
                float narg = sn[j] + b_ih[2 * H + f] + r * (sh[j] + b_hh[2 * H + f]);
                float e2 = __expf(2.f * narg);
                float nv = 1.f - 2.f / (e2 + 1.f);
                float hp = hinT[f * NN + nc];
                float hnew = (1.f - z) * nv + z * hp;
                if (act) {
                    houtT[f * NN + n] = hnew;
                    hh[(size_t)n * HP + f] = (_Float16)hnew;
                }
            }
        }
    }
}

// ---------- pool over sorted batch, reading feature-major hT ----------
__global__ void pool_T(const float* __restrict__ hT, const int* __restrict__ batch,
                       float* __restrict__ gout) {
    int wid = (blockIdx.x * blockDim.x + threadIdx.x) >> 6;
    int lane = threadIdx.x & 63;
    if (wid >= NG) return;
    int lo = 0, hi = NN;
    while (lo < hi) { int mid = (lo + hi) >> 1; if (batch[mid] < wid) lo = mid + 1; else hi = mid; }
    int beg = lo;
    lo = beg; hi = NN;
    while (lo < hi) { int mid = (lo + hi) >> 1; if (batch[mid] < wid + 1) lo = mid + 1; else hi = mid; }
    int end = lo;
    if (lane < H) {
        float acc = 0.f;
        const float* row = hT + (size_t)lane * NN;
        for (int nn2 = beg; nn2 < end; ++nn2) acc += row[nn2];
        gout[wid * H + lane] = acc;
    }
}

// ---------- dense with transposed weights ----------
template <int K, int ACT, int RB>
__global__ void dense_t(const float* __restrict__ in, const float* __restrict__ Wt,
                        const float* __restrict__ b, float* __restrict__ out,
                        int rows, int cols) {
    int t = blockIdx.x * blockDim.x + threadIdx.x;
    int ngroups = rows / RB;
    if (t >= ngroups * cols) return;
    int c = t % cols;
    int r0 = (t / cols) * RB;
    float acc[RB];
#pragma unroll
    for (int r = 0; r < RB; ++r) acc[r] = b[c];
#pragma unroll 4
    for (int k = 0; k < K; ++k) {
        float w = Wt[(size_t)k * cols + c];
#pragma unroll
        for (int r = 0; r < RB; ++r) acc[r] += in[(r0 + r) * K + k] * w;
    }
#pragma unroll
    for (int r = 0; r < RB; ++r) {
        float v = acc[r];
        v = (ACT == 0) ? fmaxf(v, 0.f) : 1.f / (1.f + expf(-v));
        out[(r0 + r) * cols + c] = v;
    }
}

static inline size_t rnd256(size_t x) { return (x + 255) & ~(size_t)255; }

extern "C" void kernel_launch(void* const* d_in, const int* in_sizes, int n_in,
                              void* d_out, int out_size, void* d_ws, size_t ws_size,
                              hipStream_t stream) {
    const float* x     = (const float*)d_in[0];
    const int*   ei    = (const int*)d_in[1];
    const int*   batch = (const int*)d_in[2];
    const float* W     = (const float*)d_in[3];
    const float* W_ih  = (const float*)d_in[4];
    const float* W_hh  = (const float*)d_in[5];
    const float* b_ih  = (const float*)d_in[6];
    const float* b_hh  = (const float*)d_in[7];
    const float* W1    = (const float*)d_in[8];
    const float* b1    = (const float*)d_in[9];
    const float* W2    = (const float*)d_in[10];
    const float* b2    = (const float*)d_in[11];
    const float* W3    = (const float*)d_in[12];
    const float* b3    = (const float*)d_in[13];
    const float* Wp    = (const float*)d_in[14];
    const float* bp    = (const float*)d_in[15];
    float* out = (float*)d_out;

    const int* src = ei;
    const int* dst = ei + NE;

    char* ws = (char*)d_ws;
    float*    aggT = (float*)ws;    ws += rnd256((size_t)H * NN * sizeof(float));
    float*    hTa  = (float*)ws;    ws += rnd256((size_t)H * NN * sizeof(float));
    float*    hTb  = (float*)ws;    ws += rnd256((size_t)H * NN * sizeof(float));
    _Float16* hh   = (_Float16*)ws; ws += rnd256((size_t)NN * HP * sizeof(_Float16));
    int*   eadj  = (int*)ws;   ws += rnd256((size_t)NE * sizeof(int));
    int*   deg   = (int*)ws;   ws += rnd256((size_t)NN * sizeof(int));
    int*   tmp   = (int*)ws;   ws += rnd256((size_t)NN * sizeof(int));
    int*   rowp  = (int*)ws;   ws += rnd256((size_t)(NN + 1) * sizeof(int));
    int*   pos   = (int*)ws;   ws += rnd256((size_t)NN * sizeof(int));
    int*   bsum  = (int*)ws;   ws += rnd256((size_t)512 * sizeof(int));
    int*   boff  = (int*)ws;   ws += rnd256((size_t)512 * sizeof(int));
    float* Wc_p  = (float*)ws; ws += rnd256((size_t)5 * H * WSTR * sizeof(float));
    float* Wh_p  = (float*)ws; ws += rnd256((size_t)H * WSTR * sizeof(float));
    float* gbuf  = (float*)ws; ws += rnd256((size_t)NG * H * sizeof(float));
    float* f1    = (float*)ws; ws += rnd256((size_t)NG * FFD * sizeof(float));
    float* f2    = (float*)ws; ws += rnd256((size_t)NG * FFD * sizeof(float));
    float* f3    = (float*)ws; ws += rnd256((size_t)NG * FFD * sizeof(float));
    float* W1t   = (float*)ws; ws += rnd256((size_t)H * FFD * sizeof(float));
    float* W2t   = (float*)ws; ws += rnd256((size_t)FFD * FFD * sizeof(float));
    float* W3t   = (float*)ws; ws += rnd256((size_t)FFD * FFD * sizeof(float));
    float* Wpt   = (float*)ws; ws += rnd256((size_t)FFD * NLB * sizeof(float));

    const int blk = 256;

    // ---- CSR build (once) ----
    hipMemsetAsync(deg, 0, (size_t)NN * sizeof(int), stream);
    hist_sh<<<FBLK, blk, 0, stream>>>(dst, deg);
    scan1<<<NBLK, SB, 0, stream>>>(deg, tmp, bsum);
    scan2<<<1, 512, 0, stream>>>(bsum, boff);
    scan3<<<(NN + 1 + blk - 1) / blk, blk, 0, stream>>>(deg, tmp, boff, rowp);
    copy_pos<<<(NN + blk - 1) / blk, blk, 0, stream>>>(rowp, pos);
    fill_sh<<<FBLK, blk, 0, stream>>>(src, dst, pos, eadj);

    // ---- weight prep + seed ----
    wc_build<<<(5 * H * H3 + blk - 1) / blk, blk, 0, stream>>>(W, W_ih, Wc_p);
    wh_pad<<<(H * H3 + blk - 1) / blk, blk, 0, stream>>>(W_hh, Wh_p);
    conv_xT<<<GT_BLOCKS, blk, 0, stream>>>(x, hTb, hh);
    tr_mat<<<(FFD * H + blk - 1) / blk, blk, 0, stream>>>(W1, W1t, FFD, H);
    tr_mat<<<(FFD * FFD + blk - 1) / blk, blk, 0, stream>>>(W2, W2t, FFD, FFD);
    tr_mat<<<(FFD * FFD + blk - 1) / blk, blk, 0, stream>>>(W3, W3t, FFD, FFD);
    tr_mat<<<(NLB * FFD + blk - 1) / blk, blk, 0, stream>>>(Wp, Wpt, NLB, FFD);

    // ---- 5 GGC layers (hTb -> hTa -> hTb -> ...) ----
    const float* hin = hTb;
    float* hout = hTa;
    for (int l = 0; l < 5; ++l) {
        gather_t<<<GA_BLOCKS, blk, 0, stream>>>(hh, rowp, eadj, aggT);
        gru_t<<<GR_BLOCKS, blk, 0, stream>>>(aggT, hin, Wc_p + (size_t)l * H * WSTR, Wh_p,
                                             b_ih, b_hh, hout, hh);
        const float* tmpp = hin; hin = hout; hout = (float*)tmpp;
    }
    // after 5 layers, final state is in hTa (hin points at it)

    // ---- pool ----
    pool_T<<<(NG * 64 + blk - 1) / blk, blk, 0, stream>>>(hin, batch, gbuf);

    // ---- MLP head ----
    dense_t<H, 0, 8><<<((NG / 8) * FFD + blk - 1) / blk, blk, 0, stream>>>(gbuf, W1t, b1, f1, NG, FFD);
    dense_t<FFD, 0, 8><<<((NG / 8) * FFD + blk - 1) / blk, blk, 0, stream>>>(f1, W2t, b2, f2, NG, FFD);
    dense_t<FFD, 0, 8><<<((NG / 8) * FFD + blk - 1) / blk, blk, 0, stream>>>(f2, W3t, b3, f3, NG, FFD);
    dense_t<FFD, 1, 8><<<((NG / 8) * NLB + blk - 1) / blk, blk, 0, stream>>>(f3, Wpt, bp, out, NG, NLB);
}

// Round 9
// 850.597 us; speedup vs baseline: 2.2225x; 2.2225x over previous
//
#include <hip/hip_runtime.h>
#include <math.h>

#define H 43
#define H3 129
#define HP 64                     // fp16 row pad -> 128B
#define HR 44                     // f32 h row stride
#define NC 176                    // B cols: 44 f-groups x 4 gates
#define KD 128                    // GEMM K: agg(64) | h(64)
#define NN 100000
#define NE 1600000
#define NG 2048
#define FFD 392
#define NLB 138
#define SB 256
#define NBLK ((NN + SB - 1) / SB) // 391
#define NXCD 8
#define SHARD 12544               // 784 16-node tiles per XCD
#define GRU_GRID (NXCD * 98)      // 784 blocks, 8 m-tiles each
#define GA_BLOCKS (NXCD * (SHARD / 4))
#define FBLK 2048
#define CHUNK ((NE + 255) / 256)  // 6250

typedef _Float16 half8 __attribute__((ext_vector_type(8)));
typedef float f32x4 __attribute__((ext_vector_type(4)));

// ---------- CSR build (XCD-sharded by dst range) ----------
__global__ void hist_sh(const int* __restrict__ dst, int* __restrict__ deg) {
    int g = blockIdx.x & (NXCD - 1);
    int i = blockIdx.x >> 3;
    int lo = g * SHARD, hi = min(lo + SHARD, NN);
    int e0 = i * CHUNK, e1 = min(NE, e0 + CHUNK);
    for (int e = e0 + threadIdx.x; e < e1; e += blockDim.x) {
        int d = dst[e];
        if (d >= lo && d < hi) atomicAdd(&deg[d], 1);
    }
}

__global__ void fill_sh(const int* __restrict__ src, const int* __restrict__ dst,
                        int* __restrict__ pos, int* __restrict__ eadj) {
    int g = blockIdx.x & (NXCD - 1);
    int i = blockIdx.x >> 3;
    int lo = g * SHARD, hi = min(lo + SHARD, NN);
    int e0 = i * CHUNK, e1 = min(NE, e0 + CHUNK);
    for (int e = e0 + threadIdx.x; e < e1; e += blockDim.x) {
        int d = dst[e];
        if (d >= lo && d < hi) {
            int slot = atomicAdd(&pos[d], 1);
            eadj[slot] = src[e];
        }
    }
}

__global__ void scan1(const int* __restrict__ deg, int* __restrict__ tmp, int* __restrict__ bsum) {
    __shared__ int s[SB];
    int i = blockIdx.x * SB + threadIdx.x;
    int v = (i < NN) ? deg[i] : 0;
    s[threadIdx.x] = v;
    __syncthreads();
    for (int off = 1; off < SB; off <<= 1) {
        int t = (threadIdx.x >= (unsigned)off) ? s[threadIdx.x - off] : 0;
        __syncthreads();
        s[threadIdx.x] += t;
        __syncthreads();
    }
    if (i < NN) tmp[i] = s[threadIdx.x];
    if (threadIdx.x == SB - 1) bsum[blockIdx.x] = s[SB - 1];
}

__global__ void scan2(const int* __restrict__ bsum, int* __restrict__ boff) {
    __shared__ int s[512];
    int v = (threadIdx.x < NBLK) ? bsum[threadIdx.x] : 0;
    s[threadIdx.x] = v;
    __syncthreads();
    for (int off = 1; off < 512; off <<= 1) {
        int t = (threadIdx.x >= (unsigned)off) ? s[threadIdx.x - off] : 0;
        __syncthreads();
        s[threadIdx.x] += t;
        __syncthreads();
    }
    boff[threadIdx.x] = s[threadIdx.x] - v; // exclusive
}

__global__ void scan3(const int* __restrict__ deg, const int* __restrict__ tmp,
                      const int* __restrict__ boff, int* __restrict__ rowptr) {
    int i = blockIdx.x * blockDim.x + threadIdx.x;
    if (i < NN) rowptr[i] = tmp[i] - deg[i] + boff[i / SB];
    if (i == NN) rowptr[NN] = NE;
}

__global__ void copy_pos(const int* __restrict__ rowptr, int* __restrict__ pos) {
    int i = blockIdx.x * blockDim.x + threadIdx.x;
    if (i < NN) pos[i] = rowptr[i];
}

// ---------- Bp: per-layer fused GRU weight matrix, fragment-packed fp16 ----------
// B[k][c], c = f*4 + gate (f<44, gate: 0=r,1=z,2=i_n,3=h_n).
// k<43: Wc=W[l]@W_ih^T (gates r/z/i_n; h_n zero). k==43: biases (agg bias slot=1).
// 64<=k<107: W_hh^T (gates r/z/h_n; i_n zero). else 0.
// Packed so lane reads B[kk*32+(lane>>4)*8+j][nt*16+(lane&15)] as one 16B load.
__global__ void bp_build(const float* __restrict__ W, const float* __restrict__ W_ih,
                         const float* __restrict__ W_hh, const float* __restrict__ b_ih,
                         const float* __restrict__ b_hh, _Float16* __restrict__ Bp) {
    int t = blockIdx.x * blockDim.x + threadIdx.x;
    if (t >= 5 * KD * NC) return;
    int l = t / (KD * NC);
    int rem = t % (KD * NC);
    int k = rem / NC, c = rem % NC;
    int f = c >> 2, gate = c & 3;
    float v = 0.f;
    if (f < H) {
        if (k < H) {
            if (gate < 3) {
                int col = gate * H + f;
                float acc = 0.f;
#pragma unroll
                for (int c2 = 0; c2 < H; ++c2)
                    acc += W[((size_t)l * H + k) * H + c2] * W_ih[col * H + c2];
                v = acc;
            }
        } else if (k == H) {
            v = (gate == 0) ? b_ih[f] + b_hh[f]
              : (gate == 1) ? b_ih[H + f] + b_hh[H + f]
              : (gate == 2) ? b_ih[2 * H + f]
                            : b_hh[2 * H + f];
        } else if (k >= 64) {
            int k2 = k - 64;
            if (k2 < H) {
                if (gate == 0)      v = W_hh[f * H + k2];
                else if (gate == 1) v = W_hh[(H + f) * H + k2];
                else if (gate == 3) v = W_hh[(2 * H + f) * H + k2];
            }
        }
    }
    int nt = c >> 4, cl = c & 15;
    int kk = k >> 5, r = k & 31;
    int lane = ((r >> 3) << 4) | cl, j = r & 7;
    Bp[(((size_t)l * 11 + nt) * 4 + kk) * 512 + lane * 8 + j] = (_Float16)v;
}

// ---------- generic transpose: At[j*R + i] = A[i*C + j] ----------
__global__ void tr_mat(const float* __restrict__ A, float* __restrict__ At, int R, int C) {
    int t = blockIdx.x * blockDim.x + threadIdx.x;
    if (t >= R * C) return;
    int i = t / C, j = t % C;
    At[(size_t)j * R + i] = A[t];
}

// ---------- seed hh (fp16 rows) and h32 (f32 rows) from x ----------
__global__ void seed_hh(const float* __restrict__ x, _Float16* __restrict__ hh) {
    int t = blockIdx.x * blockDim.x + threadIdx.x;
    if (t >= NN * HP) return;
    int n = t >> 6, f = t & (HP - 1);
    hh[t] = (f < H) ? (_Float16)x[n * H + f] : (_Float16)0.f;
}

__global__ void seed_h32(const float* __restrict__ x, float* __restrict__ h32) {
    int t = blockIdx.x * blockDim.x + threadIdx.x;
    if (t >= NN * HR) return;
    int n = t / HR, f = t % HR;
    h32[t] = (f < H) ? x[n * H + f] : 0.f;
}

// ---------- gather: aggF16[n][f] = sum of hh[src][f]; slot 43=1.0 (bias), rest 0 ----------
__global__ __launch_bounds__(256) void gather_t(const _Float16* __restrict__ hh,
                                                const int* __restrict__ rowptr,
                                                const int* __restrict__ eadj,
                                                _Float16* __restrict__ aggF16) {
    int g = blockIdx.x & (NXCD - 1);
    int i = blockIdx.x >> 3;
    int wid = g * SHARD + i * 4 + (threadIdx.x >> 6);
    int lane = threadIdx.x & 63;
    if (wid >= NN) return;
    int beg = rowptr[wid], end = rowptr[wid + 1];
    int fc = (lane < H) ? lane : 0;
    float acc = 0.f;
    for (int base = beg; base < end; base += 64) {
        int cnt = min(64, end - base);
        int idx = (base + lane < end) ? eadj[base + lane] : 0;
        int r = 0;
        for (; r + 8 <= cnt; r += 8) {
            int s0 = __shfl(idx, r + 0), s1 = __shfl(idx, r + 1);
            int s2 = __shfl(idx, r + 2), s3 = __shfl(idx, r + 3);
            int s4 = __shfl(idx, r + 4), s5 = __shfl(idx, r + 5);
            int s6 = __shfl(idx, r + 6), s7 = __shfl(idx, r + 7);
            float v0 = (float)hh[(size_t)s0 * HP + fc];
            float v1 = (float)hh[(size_t)s1 * HP + fc];
            float v2 = (float)hh[(size_t)s2 * HP + fc];
            float v3 = (float)hh[(size_t)s3 * HP + fc];
            float v4 = (float)hh[(size_t)s4 * HP + fc];
            float v5 = (float)hh[(size_t)s5 * HP + fc];
            float v6 = (float)hh[(size_t)s6 * HP + fc];
            float v7 = (float)hh[(size_t)s7 * HP + fc];
            acc += ((v0 + v1) + (v2 + v3)) + ((v4 + v5) + (v6 + v7));
        }
        if (r + 4 <= cnt) {
            int s0 = __shfl(idx, r + 0), s1 = __shfl(idx, r + 1);
            int s2 = __shfl(idx, r + 2), s3 = __shfl(idx, r + 3);
            float v0 = (float)hh[(size_t)s0 * HP + fc];
            float v1 = (float)hh[(size_t)s1 * HP + fc];
            float v2 = (float)hh[(size_t)s2 * HP + fc];
            float v3 = (float)hh[(size_t)s3 * HP + fc];
            acc += (v0 + v1) + (v2 + v3);
            r += 4;
        }
        for (; r < cnt; ++r) {
            int s = __shfl(idx, r);
            acc += (float)hh[(size_t)s * HP + fc];
        }
    }
    _Float16 w = (lane < H) ? (_Float16)acc : (lane == H) ? (_Float16)1.f : (_Float16)0.f;
    aggF16[(size_t)wid * HP + lane] = w;
}

// ---------- GRU via MFMA: [16 nodes x 128] @ [128 x 176] per tile ----------
// 4 waves/block share an m-tile; wave w owns n-tiles {w, w+4, w+8}.
// B fragments live in 12 half8 regs per wave (loaded once). Epilogue combines
// the 4 gate columns of each feature via quad shuffles; h updated in place
// (barrier between A-loads and hh writes drains vmcnt -> no read/write race).
__global__ __launch_bounds__(256) void gru_mfma(const _Float16* __restrict__ aggF16,
                                                _Float16* __restrict__ hh,
                                                float* __restrict__ h32,
                                                const _Float16* __restrict__ Bp_l) {
    int g = blockIdx.x & (NXCD - 1);
    int blk = blockIdx.x >> 3;                 // 0..97
    int lane = threadIdx.x & 63;
    int w = __builtin_amdgcn_readfirstlane(threadIdx.x >> 6);
    int m = lane & 15, kb = lane >> 4;

    half8 bf[3][4];
#pragma unroll
    for (int s = 0; s < 3; ++s) {
        int nt = w + s * 4;
        if (nt < 11) {
#pragma unroll
            for (int kk = 0; kk < 4; ++kk)
                bf[s][kk] = *(const half8*)(Bp_l + (((size_t)nt * 4 + kk) * 64 + lane) * 8);
        }
    }

    for (int it = 0; it < 8; ++it) {
        int node0 = g * SHARD + (blk * 8 + it) * 16;
        int nrow = node0 + m;
        int ncl = min(nrow, NN - 1);
        half8 a0 = *(const half8*)(aggF16 + (size_t)ncl * HP + kb * 8);
        half8 a1 = *(const half8*)(aggF16 + (size_t)ncl * HP + 32 + kb * 8);
        half8 a2 = *(const half8*)(hh + (size_t)ncl * HP + kb * 8);
        half8 a3 = *(const half8*)(hh + (size_t)ncl * HP + 32 + kb * 8);
        __syncthreads();   // all A-loads complete before any hh write below
#pragma unroll
        for (int s = 0; s < 3; ++s) {
            int nt = w + s * 4;
            if (nt >= 11) continue;
            f32x4 acc = {0.f, 0.f, 0.f, 0.f};
            acc = __builtin_amdgcn_mfma_f32_16x16x32_f16(a0, bf[s][0], acc, 0, 0, 0);
            acc = __builtin_amdgcn_mfma_f32_16x16x32_f16(a1, bf[s][1], acc, 0, 0, 0);
            acc = __builtin_amdgcn_mfma_f32_16x16x32_f16(a2, bf[s][2], acc, 0, 0, 0);
            acc = __builtin_amdgcn_mfma_f32_16x16x32_f16(a3, bf[s][3], acc, 0, 0, 0);
            int col = lane & 15;
            int f = nt * 4 + (col >> 2);
            int gate = lane & 3;
            int qbase = lane & ~3;
#pragma unroll
            for (int j = 0; j < 4; ++j) {
                float v = acc[j];
                float x0 = __shfl(v, qbase + 0);
                float x1 = __shfl(v, qbase + 1);
                float x2 = __shfl(v, qbase + 2);
                float x3 = __shfl(v, qbase + 3);
                int node = node0 + (lane >> 4) * 4 + j;
                if (gate == 0 && f < H && node < NN) {
                    float r = 1.f / (1.f + __expf(-x0));
                    float z = 1.f / (1.f + __expf(-x1));
                    float na = x2 + r * x3;
                    float e2 = __expf(2.f * na);
                    float nv = 1.f - 2.f / (e2 + 1.f);
                    float hp = h32[(size_t)node * HR + f];
                    float hnew = (1.f - z) * nv + z * hp;
                    h32[(size_t)node * HR + f] = hnew;
                    hh[(size_t)node * HP + f] = (_Float16)hnew;
                }
            }
        }
    }
}

// ---------- pool over sorted batch, reading row-major h32 ----------
__global__ void pool_r(const float* __restrict__ h32, const int* __restrict__ batch,
                       float* __restrict__ gout) {
    int wid = (blockIdx.x * blockDim.x + threadIdx.x) >> 6;
    int lane = threadIdx.x & 63;
    if (wid >= NG) return;
    int lo = 0, hi = NN;
    while (lo < hi) { int mid = (lo + hi) >> 1; if (batch[mid] < wid) lo = mid + 1; else hi = mid; }
    int beg = lo;
    lo = beg; hi = NN;
    while (lo < hi) { int mid = (lo + hi) >> 1; if (batch[mid] < wid + 1) lo = mid + 1; else hi = mid; }
    int end = lo;
    if (lane < H) {
        float acc = 0.f;
        for (int n = beg; n < end; ++n) acc += h32[(size_t)n * HR + lane];
        gout[wid * H + lane] = acc;
    }
}

// ---------- dense with transposed weights ----------
template <int K, int ACT, int RB>
__global__ void dense_t(const float* __restrict__ in, const float* __restrict__ Wt,
                        const float* __restrict__ b, float* __restrict__ out,
                        int rows, int cols) {
    int t = blockIdx.x * blockDim.x + threadIdx.x;
    int ngroups = rows / RB;
    if (t >= ngroups * cols) return;
    int c = t % cols;
    int r0 = (t / cols) * RB;
    float acc[RB];
#pragma unroll
    for (int r = 0; r < RB; ++r) acc[r] = b[c];
#pragma unroll 4
    for (int k = 0; k < K; ++k) {
        float w = Wt[(size_t)k * cols + c];
#pragma unroll
        for (int r = 0; r < RB; ++r) acc[r] += in[(r0 + r) * K + k] * w;
    }
#pragma unroll
    for (int r = 0; r < RB; ++r) {
        float v = acc[r];
        v = (ACT == 0) ? fmaxf(v, 0.f) : 1.f / (1.f + expf(-v));
        out[(r0 + r) * cols + c] = v;
    }
}

static inline size_t rnd256(size_t x) { return (x + 255) & ~(size_t)255; }

extern "C" void kernel_launch(void* const* d_in, const int* in_sizes, int n_in,
                              void* d_out, int out_size, void* d_ws, size_t ws_size,
                              hipStream_t stream) {
    const float* x     = (const float*)d_in[0];
    const int*   ei    = (const int*)d_in[1];
    const int*   batch = (const int*)d_in[2];
    const float* W     = (const float*)d_in[3];
    const float* W_ih  = (const float*)d_in[4];
    const float* W_hh  = (const float*)d_in[5];
    const float* b_ih  = (const float*)d_in[6];
    const float* b_hh  = (const float*)d_in[7];
    const float* W1    = (const float*)d_in[8];
    const float* b1    = (const float*)d_in[9];
    const float* W2    = (const float*)d_in[10];
    const float* b2    = (const float*)d_in[11];
    const float* W3    = (const float*)d_in[12];
    const float* b3    = (const float*)d_in[13];
    const float* Wp    = (const float*)d_in[14];
    const float* bp    = (const float*)d_in[15];
    float* out = (float*)d_out;

    const int* src = ei;
    const int* dst = ei + NE;

    char* ws = (char*)d_ws;
    _Float16* aggF16 = (_Float16*)ws; ws += rnd256((size_t)NN * HP * sizeof(_Float16));
    _Float16* hh     = (_Float16*)ws; ws += rnd256((size_t)NN * HP * sizeof(_Float16));
    float*    h32    = (float*)ws;    ws += rnd256((size_t)NN * HR * sizeof(float));
    int*   eadj  = (int*)ws;   ws += rnd256((size_t)NE * sizeof(int));
    int*   deg   = (int*)ws;   ws += rnd256((size_t)NN * sizeof(int));
    int*   tmp   = (int*)ws;   ws += rnd256((size_t)NN * sizeof(int));
    int*   rowp  = (int*)ws;   ws += rnd256((size_t)(NN + 1) * sizeof(int));
    int*   pos   = (int*)ws;   ws += rnd256((size_t)NN * sizeof(int));
    int*   bsum  = (int*)ws;   ws += rnd256((size_t)512 * sizeof(int));
    int*   boff  = (int*)ws;   ws += rnd256((size_t)512 * sizeof(int));
    _Float16* Bp = (_Float16*)ws; ws += rnd256((size_t)5 * 11 * 4 * 512 * sizeof(_Float16));
    float* gbuf  = (float*)ws; ws += rnd256((size_t)NG * H * sizeof(float));
    float* f1    = (float*)ws; ws += rnd256((size_t)NG * FFD * sizeof(float));
    float* f2    = (float*)ws; ws += rnd256((size_t)NG * FFD * sizeof(float));
    float* f3    = (float*)ws; ws += rnd256((size_t)NG * FFD * sizeof(float));
    float* W1t   = (float*)ws; ws += rnd256((size_t)H * FFD * sizeof(float));
    float* W2t   = (float*)ws; ws += rnd256((size_t)FFD * FFD * sizeof(float));
    float* W3t   = (float*)ws; ws += rnd256((size_t)FFD * FFD * sizeof(float));
    float* Wpt   = (float*)ws; ws += rnd256((size_t)FFD * NLB * sizeof(float));

    const int blk = 256;

    // ---- CSR build (once) ----
    hipMemsetAsync(deg, 0, (size_t)NN * sizeof(int), stream);
    hist_sh<<<FBLK, blk, 0, stream>>>(dst, deg);
    scan1<<<NBLK, SB, 0, stream>>>(deg, tmp, bsum);
    scan2<<<1, 512, 0, stream>>>(bsum, boff);
    scan3<<<(NN + 1 + blk - 1) / blk, blk, 0, stream>>>(deg, tmp, boff, rowp);
    copy_pos<<<(NN + blk - 1) / blk, blk, 0, stream>>>(rowp, pos);
    fill_sh<<<FBLK, blk, 0, stream>>>(src, dst, pos, eadj);

    // ---- weight prep + seed ----
    bp_build<<<(5 * KD * NC + blk - 1) / blk, blk, 0, stream>>>(W, W_ih, W_hh, b_ih, b_hh, Bp);
    seed_hh<<<(NN * HP + blk - 1) / blk, blk, 0, stream>>>(x, hh);
    seed_h32<<<(NN * HR + blk - 1) / blk, blk, 0, stream>>>(x, h32);
    tr_mat<<<(FFD * H + blk - 1) / blk, blk, 0, stream>>>(W1, W1t, FFD, H);
    tr_mat<<<(FFD * FFD + blk - 1) / blk, blk, 0, stream>>>(W2, W2t, FFD, FFD);
    tr_mat<<<(FFD * FFD + blk - 1) / blk, blk, 0, stream>>>(W3, W3t, FFD, FFD);
    tr_mat<<<(NLB * FFD + blk - 1) / blk, blk, 0, stream>>>(Wp, Wpt, NLB, FFD);

    // ---- 5 GGC layers ----
    for (int l = 0; l < 5; ++l) {
        gather_t<<<GA_BLOCKS, blk, 0, stream>>>(hh, rowp, eadj, aggF16);
        gru_mfma<<<GRU_GRID, blk, 0, stream>>>(aggF16, hh, h32,
                                               Bp + (size_t)l * 11 * 4 * 512);
    }

    // ---- pool ----
    pool_r<<<(NG * 64 + blk - 1) / blk, blk, 0, stream>>>(h32, batch, gbuf);

    // ---- MLP head ----
    dense_t<H, 0, 8><<<((NG / 8) * FFD + blk - 1) / blk, blk, 0, stream>>>(gbuf, W1t, b1, f1, NG, FFD);
    dense_t<FFD, 0, 8><<<((NG / 8) * FFD + blk - 1) / blk, blk, 0, stream>>>(f1, W2t, b2, f2, NG, FFD);
    dense_t<FFD, 0, 8><<<((NG / 8) * FFD + blk - 1) / blk, blk, 0, stream>>>(f2, W3t, b3, f3, NG, FFD);
    dense_t<FFD, 1, 8><<<((NG / 8) * NLB + blk - 1) / blk, blk, 0, stream>>>(f3, Wpt, bp, out, NG, NLB);
}